// Round 10
// baseline (1826.737 us; speedup 1.0000x reference)
//
#include <hip/hip_runtime.h>
#include <cmath>

#define DD 256
#define NPW 32             // nodes per wave in pooling

static inline int cdiv(long a, long b) { return (int)((a + b - 1) / b); }

__device__ __forceinline__ void atomic_max_float(float* addr, float value) {
    if (value >= 0.0f) atomicMax((int*)addr, __float_as_int(value));
    else atomicMin((unsigned int*)addr, __float_as_uint(value));
}

// ---------------- init: zero out/sg/bsum/..., -inf bmax ----------------
__global__ void init_kernel(float* __restrict__ out, long nout,
                            float* __restrict__ zro, long nz,
                            float* __restrict__ neg, long nneg) {
    long i = (long)blockIdx.x * blockDim.x + threadIdx.x;
    long st = (long)gridDim.x * blockDim.x;
    for (long t = i; t < nout; t += st) out[t] = 0.0f;
    for (long t = i; t < nz; t += st) zro[t] = 0.0f;
    for (long t = i; t < nneg; t += st) neg[t] = -INFINITY;
}

// ---------------- wsum: sum of the (1,D) score weight rows ----------------
__global__ void wsum_kernel(const float* __restrict__ w0, const float* __restrict__ w1,
                            float* __restrict__ o0, float* __restrict__ o1) {
    __shared__ float sm[DD];
    const float* w = (blockIdx.x == 0) ? w0 : w1;
    sm[threadIdx.x] = w[threadIdx.x];
    __syncthreads();
    for (int s = DD / 2; s > 0; s >>= 1) {
        if (threadIdx.x < s) sm[threadIdx.x] += sm[threadIdx.x + s];
        __syncthreads();
    }
    if (threadIdx.x == 0) {
        if (blockIdx.x == 0) *o0 = sm[0]; else *o1 = sm[0];
    }
}

// ---------------- kqv: per-node 3 dot products; kv packed float2; track max|k| ----------------
__global__ void kqv_kernel(const float* __restrict__ x, const float* __restrict__ W,
                           const float* __restrict__ bias,
                           float2* __restrict__ kv, float* __restrict__ q,
                           float* __restrict__ maxk, int N) {
    const int lane = threadIdx.x & 63;
    const int wib  = threadIdx.x >> 6;
    const int wpb  = blockDim.x >> 6;
    long wid = (long)blockIdx.x * wpb + wib;
    long nw  = (long)gridDim.x * wpb;
    float wk[4], wq[4], wv[4];
#pragma unroll
    for (int i = 0; i < 4; i++) {
        int d = lane * 4 + i;
        wk[i] = W[d * 3 + 0];
        wq[i] = W[d * 3 + 1];
        wv[i] = W[d * 3 + 2];
    }
    const float bk = bias[0], bq = bias[1], bv = bias[2];
    const float4* x4 = (const float4*)x;
    float amax = 0.0f;
    for (long n = wid; n < N; n += nw) {
        float4 xv = x4[n * 64 + lane];
        float pk = xv.x * wk[0] + xv.y * wk[1] + xv.z * wk[2] + xv.w * wk[3];
        float pq = xv.x * wq[0] + xv.y * wq[1] + xv.z * wq[2] + xv.w * wq[3];
        float pv = xv.x * wv[0] + xv.y * wv[1] + xv.z * wv[2] + xv.w * wv[3];
#pragma unroll
        for (int mk = 1; mk < 64; mk <<= 1) {
            pk += __shfl_xor(pk, mk, 64);
            pq += __shfl_xor(pq, mk, 64);
            pv += __shfl_xor(pv, mk, 64);
        }
        float kk = pk + bk;
        amax = fmaxf(amax, fabsf(kk));
        if (lane == 0) {
            kv[n] = make_float2(kk, pv + bv);
            q[n]  = pq + bq;
        }
    }
    if (lane == 0) atomic_max_float(maxk, amax);
}

// ---------------- prep: logit upper-bound coefficients ----------------
__global__ void prep_kernel(const float* a_ii, const float* p_ii,
                            const float* a_ni, const float* p_ni,
                            const float* a_in, const float* p_in,
                            const float* maxk_i, const float* maxk_n,
                            float* __restrict__ C_inst, float* __restrict__ C_net) {
    if (threadIdx.x == 0 && blockIdx.x == 0) {
        float ci = fmaxf(fabsf(a_ii[0] * p_ii[0]) * maxk_i[0],
                         fabsf(a_ni[0] * p_ni[0]) * maxk_n[0]);
        float cn = fabsf(a_in[0] * p_in[0]) * maxk_i[0];
        *C_inst = ci;
        *C_net  = cn;
    }
}

// ---------------- edge accum: direct per-edge exp + global atomic into sg ----------------
// ex = exp(q[d]*k[s]*coef - |q[d]|*C) is order-free (uniform per-dst bound), so no
// binning/privatization needed: gathers and sg are all L2-resident (~4 MB total).
__global__ __launch_bounds__(256) void edge_accum_kernel(
    const int* __restrict__ src, const int* __restrict__ dst,
    const float2* __restrict__ kv, const float* __restrict__ q,
    const float* __restrict__ a_p, const float* __restrict__ p_p,
    const float* __restrict__ msc_p, const float* __restrict__ C_p,
    float2* __restrict__ sg, int E) {
    const float coef = a_p[0] * p_p[0];
    const float msc  = msc_p[0];
    const float C    = C_p[0];
    float* sgf = (float*)sg;
    long i  = (long)blockIdx.x * blockDim.x + threadIdx.x;
    long st = (long)gridDim.x * blockDim.x;
    for (long e = i; e < E; e += st) {
        int d = dst[e], s = src[e];
        float2 kvv = kv[s];
        float qd = q[d];
        float ex = __expf(qd * (kvv.x * coef) - fabsf(qd) * C);
        unsafeAtomicAdd(&sgf[2L * d],     ex);
        unsafeAtomicAdd(&sgf[2L * d + 1], ex * (kvv.y * msc));
    }
}

// ---------------- fused node epilogue + batch segment max ----------------
__global__ void score_bmax_kernel(const float2* __restrict__ sg,
                                  const float* __restrict__ outw_p, const float* __restrict__ outb_p,
                                  const float* __restrict__ wsum_p, const float* __restrict__ bsc_p,
                                  const int* __restrict__ batch,
                                  float* __restrict__ score, float* __restrict__ bmax, int N) {
    const float ow = outw_p[0], ob = outb_p[0];
    const float wsum = wsum_p[0], badd = bsc_p[0] * (float)DD;
    const int lane = threadIdx.x & 63;
    long st = (long)gridDim.x * blockDim.x;
    for (long base = (long)blockIdx.x * blockDim.x; base < N; base += st) {
        long n = base + threadIdx.x;
        bool act = (n < N);
        int b = act ? batch[n] : -1;
        float v = -INFINITY;
        if (act) {
            float2 t = sg[n];
            float a  = t.y / (t.x + 1e-30f);
            float at = 0.5f * a * (1.0f + erff(a * 0.7071067811865475f));
            v = (at * ow + ob) * wsum + badd;
            score[n] = v;
        }
        int b0 = __shfl(b, 0, 64);
        if (__all(b == b0)) {
#pragma unroll
            for (int mk = 1; mk < 64; mk <<= 1) v = fmaxf(v, __shfl_xor(v, mk, 64));
            if (lane == 0 && b0 >= 0) atomic_max_float(&bmax[b0], v);
        } else if (act) {
            atomic_max_float(&bmax[b], v);
        }
    }
}

// ---------------- batch segment exp-sum; stores per-node e ----------------
__global__ void bsum_kernel(const float* __restrict__ score, const int* __restrict__ batch,
                            const float* __restrict__ bmax,
                            float* __restrict__ bsum, float* __restrict__ ew, int N) {
    const int lane = threadIdx.x & 63;
    long st = (long)gridDim.x * blockDim.x;
    for (long base = (long)blockIdx.x * blockDim.x; base < N; base += st) {
        long n = base + threadIdx.x;
        bool act = (n < N);
        int b = act ? batch[n] : -1;
        float ex = 0.0f;
        if (act) {
            ex = __expf(score[n] - bmax[b]);
            ew[n] = ex;
        }
        int b0 = __shfl(b, 0, 64);
        if (__all(b == b0)) {
#pragma unroll
            for (int mk = 1; mk < 64; mk <<= 1) ex += __shfl_xor(ex, mk, 64);
            if (lane == 0 && b0 >= 0) unsafeAtomicAdd(&bsum[b0], ex);
        } else if (act) {
            unsafeAtomicAdd(&bsum[b], ex);
        }
    }
}

// ---------------- pooling: wave per NPW-node run, flush at batch boundaries ----------------
__global__ void pool_kernel(const float* __restrict__ x, const float* __restrict__ ew,
                            const int* __restrict__ batch, const float* __restrict__ bsum,
                            float* __restrict__ out, int N) {
    const int lane = threadIdx.x & 63;
    const int wib  = threadIdx.x >> 6;
    const int wpb  = blockDim.x >> 6;
    long w = (long)blockIdx.x * wpb + wib;
    long n0 = w * NPW;
    if (n0 >= N) return;
    long n1 = n0 + NPW; if (n1 > N) n1 = N;
    const float4* x4 = (const float4*)x;
    float4 acc = make_float4(0.f, 0.f, 0.f, 0.f);
    int pb = batch[n0];
    for (long n = n0; n < n1; ++n) {
        int b = batch[n];
        if (b != pb) {
            float* p = out + (long)pb * DD + lane * 4;
            unsafeAtomicAdd(p + 0, acc.x);
            unsafeAtomicAdd(p + 1, acc.y);
            unsafeAtomicAdd(p + 2, acc.z);
            unsafeAtomicAdd(p + 3, acc.w);
            acc = make_float4(0.f, 0.f, 0.f, 0.f);
            pb = b;
        }
        float wt = ew[n] / (bsum[b] + 1e-16f);
        float4 xv = x4[n * 64 + lane];
        acc.x += wt * xv.x;
        acc.y += wt * xv.y;
        acc.z += wt * xv.z;
        acc.w += wt * xv.w;
    }
    float* p = out + (long)pb * DD + lane * 4;
    unsafeAtomicAdd(p + 0, acc.x);
    unsafeAtomicAdd(p + 1, acc.y);
    unsafeAtomicAdd(p + 2, acc.z);
    unsafeAtomicAdd(p + 3, acc.w);
}

extern "C" void kernel_launch(void* const* d_in, const int* in_sizes, int n_in,
                              void* d_out, int out_size, void* d_ws, size_t ws_size,
                              hipStream_t stream) {
    const float* x_i    = (const float*)d_in[0];
    const float* x_n    = (const float*)d_in[1];
    const int*   e_ii   = (const int*)d_in[2];
    const int*   e_in   = (const int*)d_in[3];
    const int*   e_ni   = (const int*)d_in[4];
    const int*   bat_i  = (const int*)d_in[5];
    const int*   bat_n  = (const int*)d_in[6];
    const float* W_i    = (const float*)d_in[7];
    const float* bW_i   = (const float*)d_in[8];
    const float* W_n    = (const float*)d_in[9];
    const float* bW_n   = (const float*)d_in[10];
    const float* a_ii   = (const float*)d_in[11];
    const float* m_ii   = (const float*)d_in[12];
    const float* p_ii   = (const float*)d_in[13];
    const float* a_in   = (const float*)d_in[14];
    const float* m_in   = (const float*)d_in[15];
    const float* p_in   = (const float*)d_in[16];
    const float* a_ni   = (const float*)d_in[17];
    const float* m_ni   = (const float*)d_in[18];
    const float* p_ni   = (const float*)d_in[19];
    const float* outw_i = (const float*)d_in[20];
    const float* outb_i = (const float*)d_in[21];
    const float* outw_n = (const float*)d_in[22];
    const float* outb_n = (const float*)d_in[23];
    const float* w_i    = (const float*)d_in[24];
    const float* b_i    = (const float*)d_in[25];
    const float* w_n    = (const float*)d_in[26];
    const float* b_n    = (const float*)d_in[27];

    const int NI  = in_sizes[0] / DD;
    const int NN  = in_sizes[1] / DD;
    const int Eii = in_sizes[2] / 2;
    const int Ein = in_sizes[3] / 2;
    const int Eni = in_sizes[4] / 2;
    const int B   = out_size / (2 * DD);
    float* out = (float*)d_out;

    float* ws = (float*)d_ws;
    float2* kv_i = (float2*)ws;  ws += 2L * NI;
    float*  q_i  = ws;           ws += NI;
    float2* kv_n = (float2*)ws;  ws += 2L * NN;
    float*  q_n  = ws;           ws += NN;
    float* sc_i = ws;   ws += NI;
    float* sc_n = ws;   ws += NN;
    float* ew_i = ws;   ws += NI;
    float* ew_n = ws;   ws += NN;
    // zero-init region (sg must be zeroed: edge_accum merges with atomics)
    float* zro0 = ws;
    float2* sg_i = (float2*)ws;  ws += 2L * NI;
    float2* sg_n = (float2*)ws;  ws += 2L * NN;
    float* bsum_i = ws; ws += B;
    float* bsum_n = ws; ws += B;
    float* maxk_i = ws; ws += 1;
    float* maxk_n = ws; ws += 1;
    float* wsum_i = ws; ws += 1;
    float* wsum_n = ws; ws += 1;
    float* C_inst = ws; ws += 1;
    float* C_net  = ws; ws += 1;
    long n_zro = (long)(ws - zro0);
    // -inf region
    float* neg0 = ws;
    float* bmax_i = ws; ws += B;
    float* bmax_n = ws; ws += B;
    long n_neg = (long)(ws - neg0);

    dim3 blk(256);

    init_kernel<<<256, blk, 0, stream>>>(out, (long)out_size, zro0, n_zro, neg0, n_neg);
    wsum_kernel<<<2, blk, 0, stream>>>(w_i, w_n, wsum_i, wsum_n);

    kqv_kernel<<<2048, blk, 0, stream>>>(x_i, W_i, bW_i, kv_i, q_i, maxk_i, NI);
    kqv_kernel<<<2048, blk, 0, stream>>>(x_n, W_n, bW_n, kv_n, q_n, maxk_n, NN);

    prep_kernel<<<1, 64, 0, stream>>>(a_ii, p_ii, a_ni, p_ni, a_in, p_in,
                                      maxk_i, maxk_n, C_inst, C_net);

    // type ii -> sg_i
    edge_accum_kernel<<<2048, blk, 0, stream>>>(e_ii, e_ii + Eii, kv_i, q_i,
                                                a_ii, p_ii, m_ii, C_inst, sg_i, Eii);
    // type ni -> sg_i
    edge_accum_kernel<<<2048, blk, 0, stream>>>(e_ni, e_ni + Eni, kv_n, q_i,
                                                a_ni, p_ni, m_ni, C_inst, sg_i, Eni);
    // type in -> sg_n
    edge_accum_kernel<<<2048, blk, 0, stream>>>(e_in, e_in + Ein, kv_i, q_n,
                                                a_in, p_in, m_in, C_net, sg_n, Ein);

    score_bmax_kernel<<<cdiv(NI, 256), blk, 0, stream>>>(sg_i, outw_i, outb_i, wsum_i, b_i,
                                                         bat_i, sc_i, bmax_i, NI);
    score_bmax_kernel<<<cdiv(NN, 256), blk, 0, stream>>>(sg_n, outw_n, outb_n, wsum_n, b_n,
                                                         bat_n, sc_n, bmax_n, NN);
    bsum_kernel<<<cdiv(NI, 256), blk, 0, stream>>>(sc_i, bat_i, bmax_i, bsum_i, ew_i, NI);
    bsum_kernel<<<cdiv(NN, 256), blk, 0, stream>>>(sc_n, bat_n, bmax_n, bsum_n, ew_n, NN);

    pool_kernel<<<cdiv(cdiv(NI, NPW), 4), blk, 0, stream>>>(x_i, ew_i, bat_i, bsum_i, out, NI);
    pool_kernel<<<cdiv(cdiv(NN, NPW), 4), blk, 0, stream>>>(x_n, ew_n, bat_n, bsum_n, out + (long)B * DD, NN);
}

// Round 11
// 1241.903 us; speedup vs baseline: 1.4709x; 1.4709x over previous
//
#include <hip/hip_runtime.h>
#include <cmath>

#define DD 256
#define BINW 1024          // destinations per bin (fits LDS accumulators)
#define CAP 16384          // payload slots per bin (mean 15360, +8 sigma)
#define SL 4096            // edges per hist/fill block
#define NPW 32             // nodes per wave in pooling
#define ASPLIT 4           // blocks per bin in accum

static inline int cdiv(long a, long b) { return (int)((a + b - 1) / b); }

__device__ __forceinline__ void atomic_max_float(float* addr, float value) {
    if (value >= 0.0f) atomicMax((int*)addr, __float_as_int(value));
    else atomicMin((unsigned int*)addr, __float_as_uint(value));
}

// ---------------- init: zero out/sg/bsum/..., -inf bmax ----------------
__global__ void init_kernel(float* __restrict__ out, long nout,
                            float* __restrict__ zro, long nz,
                            float* __restrict__ neg, long nneg) {
    long i = (long)blockIdx.x * blockDim.x + threadIdx.x;
    long st = (long)gridDim.x * blockDim.x;
    for (long t = i; t < nout; t += st) out[t] = 0.0f;
    for (long t = i; t < nz; t += st) zro[t] = 0.0f;
    for (long t = i; t < nneg; t += st) neg[t] = -INFINITY;
}

// ---------------- wsum: sum of the (1,D) score weight rows ----------------
__global__ void wsum_kernel(const float* __restrict__ w0, const float* __restrict__ w1,
                            float* __restrict__ o0, float* __restrict__ o1) {
    __shared__ float sm[DD];
    const float* w = (blockIdx.x == 0) ? w0 : w1;
    sm[threadIdx.x] = w[threadIdx.x];
    __syncthreads();
    for (int s = DD / 2; s > 0; s >>= 1) {
        if (threadIdx.x < s) sm[threadIdx.x] += sm[threadIdx.x + s];
        __syncthreads();
    }
    if (threadIdx.x == 0) {
        if (blockIdx.x == 0) *o0 = sm[0]; else *o1 = sm[0];
    }
}

// ---------------- kqv: per-node 3 dot products; kv packed float2; track max|k| ----------------
__global__ void kqv_kernel(const float* __restrict__ x, const float* __restrict__ W,
                           const float* __restrict__ bias,
                           float2* __restrict__ kv, float* __restrict__ q,
                           float* __restrict__ maxk, int N) {
    const int lane = threadIdx.x & 63;
    const int wib  = threadIdx.x >> 6;
    const int wpb  = blockDim.x >> 6;
    long wid = (long)blockIdx.x * wpb + wib;
    long nw  = (long)gridDim.x * wpb;
    float wk[4], wq[4], wv[4];
#pragma unroll
    for (int i = 0; i < 4; i++) {
        int d = lane * 4 + i;
        wk[i] = W[d * 3 + 0];
        wq[i] = W[d * 3 + 1];
        wv[i] = W[d * 3 + 2];
    }
    const float bk = bias[0], bq = bias[1], bv = bias[2];
    const float4* x4 = (const float4*)x;
    float amax = 0.0f;
    for (long n = wid; n < N; n += nw) {
        float4 xv = x4[n * 64 + lane];
        float pk = xv.x * wk[0] + xv.y * wk[1] + xv.z * wk[2] + xv.w * wk[3];
        float pq = xv.x * wq[0] + xv.y * wq[1] + xv.z * wq[2] + xv.w * wq[3];
        float pv = xv.x * wv[0] + xv.y * wv[1] + xv.z * wv[2] + xv.w * wv[3];
#pragma unroll
        for (int mk = 1; mk < 64; mk <<= 1) {
            pk += __shfl_xor(pk, mk, 64);
            pq += __shfl_xor(pq, mk, 64);
            pv += __shfl_xor(pv, mk, 64);
        }
        float kk = pk + bk;
        amax = fmaxf(amax, fabsf(kk));
        if (lane == 0) {
            kv[n] = make_float2(kk, pv + bv);
            q[n]  = pq + bq;
        }
    }
    if (lane == 0) atomic_max_float(maxk, amax);
}

// ---------------- prep: logit upper-bound coefficients ----------------
__global__ void prep_kernel(const float* a_ii, const float* p_ii,
                            const float* a_ni, const float* p_ni,
                            const float* a_in, const float* p_in,
                            const float* maxk_i, const float* maxk_n,
                            float* __restrict__ C_inst, float* __restrict__ C_net) {
    if (threadIdx.x == 0 && blockIdx.x == 0) {
        float ci = fmaxf(fabsf(a_ii[0] * p_ii[0]) * maxk_i[0],
                         fabsf(a_ni[0] * p_ni[0]) * maxk_n[0]);
        float cn = fabsf(a_in[0] * p_in[0]) * maxk_i[0];
        *C_inst = ci;
        *C_net  = cn;
    }
}

// ---------------- hist: per-block bin histogram (plain stores, no global atomics) ----------------
__global__ __launch_bounds__(256) void hist_kernel(const int* __restrict__ dst,
                                                   int* __restrict__ hist, int E) {
    __shared__ int h[256];
    const int tid = threadIdx.x;
    h[tid] = 0;
    __syncthreads();
    long e0 = (long)blockIdx.x * SL;
    long e1 = e0 + SL; if (e1 > E) e1 = E;
    for (long e = e0 + tid; e < e1; e += 256) {
        atomicAdd(&h[dst[e] >> 10], 1);
    }
    __syncthreads();
    hist[(long)blockIdx.x * 256 + tid] = h[tid];
}

// ---------------- scan: per-bin exclusive prefix over blocks -> per-block bases ----------------
// grid = nbins, block = 64 (one wave). base[blk][b] = b*CAP + prefix; cnt[b] = total.
__global__ void scan_kernel(const int* __restrict__ hist, int* __restrict__ base,
                            int* __restrict__ cnt, int nblk) {
    const int b = blockIdx.x;
    const int lane = threadIdx.x;
    int running = 0;
    for (int blk0 = 0; blk0 < nblk; blk0 += 64) {
        int blk = blk0 + lane;
        int v = (blk < nblk) ? hist[(long)blk * 256 + b] : 0;
        int x = v;
#pragma unroll
        for (int off = 1; off < 64; off <<= 1) {
            int y = __shfl_up(x, off, 64);
            if (lane >= off) x += y;
        }
        if (blk < nblk) base[(long)blk * 256 + b] = b * CAP + running + (x - v);
        running += __shfl(x, 63, 64);
    }
    if (lane == 0) cnt[b] = running;
}

// ---------------- fill: scatter packed (src<<10 | dst&1023) at precomputed bases ----------------
__global__ __launch_bounds__(256) void fill_kernel(
    const int* __restrict__ src, const int* __restrict__ dst,
    const int* __restrict__ base_g, unsigned int* __restrict__ pay, int E) {
    __shared__ int bl[256];
    __shared__ int off[256];
    const int tid = threadIdx.x;
    bl[tid] = base_g[(long)blockIdx.x * 256 + tid];
    off[tid] = 0;
    __syncthreads();
    long e0 = (long)blockIdx.x * SL;
    long e1 = e0 + SL; if (e1 > E) e1 = E;
    for (long e = e0 + tid; e < e1; e += 256) {
        int d = dst[e], s = src[e];
        int b = d >> 10;
        int o = atomicAdd(&off[b], 1);
        long slot = (long)bl[b] + o;
        if (slot < (long)(b + 1) * CAP) {
            pay[slot] = ((unsigned int)s << 10) | (unsigned int)(d & (BINW - 1));
        }
    }
}

// ---------------- accum: per-bin-stripe LDS accumulation, atomic merge into sg ----------------
__global__ __launch_bounds__(256) void accum_kernel(
    const unsigned int* __restrict__ pay, const int* __restrict__ cnt,
    const float2* __restrict__ kv, const float* __restrict__ q,
    const float* __restrict__ a_p, const float* __restrict__ p_p,
    const float* __restrict__ msc_p, const float* __restrict__ C_p,
    float2* __restrict__ sg, int N) {
    __shared__ float accS[BINW];
    __shared__ float accG[BINW];
    __shared__ float2 qm[BINW];
    const int tid = threadIdx.x;
    const int b  = blockIdx.x >> 2;      // ASPLIT = 4
    const int sp = blockIdx.x & 3;
    const float C = C_p[0];
    const float coef = a_p[0] * p_p[0];
    const float msc  = msc_p[0];
    for (int i = tid; i < BINW; i += 256) {
        accS[i] = 0.0f; accG[i] = 0.0f;
        int d = b * BINW + i;
        float qd = (d < N) ? q[d] : 0.0f;
        qm[i] = make_float2(qd, fabsf(qd) * C);
    }
    __syncthreads();
    long s0 = (long)b * CAP;
    long c = cnt[b];
    if (c > CAP) c = CAP;
    long chunk = (c + ASPLIT - 1) / ASPLIT;
    long a0 = s0 + (long)sp * chunk;
    long a1 = a0 + chunk;
    long send = s0 + c;
    if (a1 > send) a1 = send;
    for (long e = a0 + tid; e < a1; e += 256) {
        unsigned int pk = pay[e];
        int s  = (int)(pk >> 10);
        int di = (int)(pk & (BINW - 1));
        float2 kvv = kv[s];
        float2 qv = qm[di];
        float ex = __expf(qv.x * (kvv.x * coef) - qv.y);
        atomicAdd(&accS[di], ex);
        atomicAdd(&accG[di], ex * (kvv.y * msc));
    }
    __syncthreads();
    float* sgf = (float*)sg;
    for (int i = tid; i < BINW; i += 256) {
        int d = b * BINW + i;
        if (d < N) {
            float s = accS[i];
            if (s != 0.0f) {
                unsafeAtomicAdd(&sgf[2L * d],     s);
                unsafeAtomicAdd(&sgf[2L * d + 1], accG[i]);
            }
        }
    }
}

// ---------------- fused node epilogue + batch segment max ----------------
__global__ void score_bmax_kernel(const float2* __restrict__ sg,
                                  const float* __restrict__ outw_p, const float* __restrict__ outb_p,
                                  const float* __restrict__ wsum_p, const float* __restrict__ bsc_p,
                                  const int* __restrict__ batch,
                                  float* __restrict__ score, float* __restrict__ bmax, int N) {
    const float ow = outw_p[0], ob = outb_p[0];
    const float wsum = wsum_p[0], badd = bsc_p[0] * (float)DD;
    const int lane = threadIdx.x & 63;
    long st = (long)gridDim.x * blockDim.x;
    for (long base = (long)blockIdx.x * blockDim.x; base < N; base += st) {
        long n = base + threadIdx.x;
        bool act = (n < N);
        int b = act ? batch[n] : -1;
        float v = -INFINITY;
        if (act) {
            float2 t = sg[n];
            float a  = t.y / (t.x + 1e-30f);
            float at = 0.5f * a * (1.0f + erff(a * 0.7071067811865475f));
            v = (at * ow + ob) * wsum + badd;
            score[n] = v;
        }
        int b0 = __shfl(b, 0, 64);
        if (__all(b == b0)) {
#pragma unroll
            for (int mk = 1; mk < 64; mk <<= 1) v = fmaxf(v, __shfl_xor(v, mk, 64));
            if (lane == 0 && b0 >= 0) atomic_max_float(&bmax[b0], v);
        } else if (act) {
            atomic_max_float(&bmax[b], v);
        }
    }
}

// ---------------- batch segment exp-sum; stores per-node e ----------------
__global__ void bsum_kernel(const float* __restrict__ score, const int* __restrict__ batch,
                            const float* __restrict__ bmax,
                            float* __restrict__ bsum, float* __restrict__ ew, int N) {
    const int lane = threadIdx.x & 63;
    long st = (long)gridDim.x * blockDim.x;
    for (long base = (long)blockIdx.x * blockDim.x; base < N; base += st) {
        long n = base + threadIdx.x;
        bool act = (n < N);
        int b = act ? batch[n] : -1;
        float ex = 0.0f;
        if (act) {
            ex = __expf(score[n] - bmax[b]);
            ew[n] = ex;
        }
        int b0 = __shfl(b, 0, 64);
        if (__all(b == b0)) {
#pragma unroll
            for (int mk = 1; mk < 64; mk <<= 1) ex += __shfl_xor(ex, mk, 64);
            if (lane == 0 && b0 >= 0) unsafeAtomicAdd(&bsum[b0], ex);
        } else if (act) {
            unsafeAtomicAdd(&bsum[b], ex);
        }
    }
}

// ---------------- pooling: wave per NPW-node run, flush at batch boundaries ----------------
__global__ void pool_kernel(const float* __restrict__ x, const float* __restrict__ ew,
                            const int* __restrict__ batch, const float* __restrict__ bsum,
                            float* __restrict__ out, int N) {
    const int lane = threadIdx.x & 63;
    const int wib  = threadIdx.x >> 6;
    const int wpb  = blockDim.x >> 6;
    long w = (long)blockIdx.x * wpb + wib;
    long n0 = w * NPW;
    if (n0 >= N) return;
    long n1 = n0 + NPW; if (n1 > N) n1 = N;
    const float4* x4 = (const float4*)x;
    float4 acc = make_float4(0.f, 0.f, 0.f, 0.f);
    int pb = batch[n0];
    for (long n = n0; n < n1; ++n) {
        int b = batch[n];
        if (b != pb) {
            float* p = out + (long)pb * DD + lane * 4;
            unsafeAtomicAdd(p + 0, acc.x);
            unsafeAtomicAdd(p + 1, acc.y);
            unsafeAtomicAdd(p + 2, acc.z);
            unsafeAtomicAdd(p + 3, acc.w);
            acc = make_float4(0.f, 0.f, 0.f, 0.f);
            pb = b;
        }
        float wt = ew[n] / (bsum[b] + 1e-16f);
        float4 xv = x4[n * 64 + lane];
        acc.x += wt * xv.x;
        acc.y += wt * xv.y;
        acc.z += wt * xv.z;
        acc.w += wt * xv.w;
    }
    float* p = out + (long)pb * DD + lane * 4;
    unsafeAtomicAdd(p + 0, acc.x);
    unsafeAtomicAdd(p + 1, acc.y);
    unsafeAtomicAdd(p + 2, acc.z);
    unsafeAtomicAdd(p + 3, acc.w);
}

extern "C" void kernel_launch(void* const* d_in, const int* in_sizes, int n_in,
                              void* d_out, int out_size, void* d_ws, size_t ws_size,
                              hipStream_t stream) {
    const float* x_i    = (const float*)d_in[0];
    const float* x_n    = (const float*)d_in[1];
    const int*   e_ii   = (const int*)d_in[2];
    const int*   e_in   = (const int*)d_in[3];
    const int*   e_ni   = (const int*)d_in[4];
    const int*   bat_i  = (const int*)d_in[5];
    const int*   bat_n  = (const int*)d_in[6];
    const float* W_i    = (const float*)d_in[7];
    const float* bW_i   = (const float*)d_in[8];
    const float* W_n    = (const float*)d_in[9];
    const float* bW_n   = (const float*)d_in[10];
    const float* a_ii   = (const float*)d_in[11];
    const float* m_ii   = (const float*)d_in[12];
    const float* p_ii   = (const float*)d_in[13];
    const float* a_in   = (const float*)d_in[14];
    const float* m_in   = (const float*)d_in[15];
    const float* p_in   = (const float*)d_in[16];
    const float* a_ni   = (const float*)d_in[17];
    const float* m_ni   = (const float*)d_in[18];
    const float* p_ni   = (const float*)d_in[19];
    const float* outw_i = (const float*)d_in[20];
    const float* outb_i = (const float*)d_in[21];
    const float* outw_n = (const float*)d_in[22];
    const float* outb_n = (const float*)d_in[23];
    const float* w_i    = (const float*)d_in[24];
    const float* b_i    = (const float*)d_in[25];
    const float* w_n    = (const float*)d_in[26];
    const float* b_n    = (const float*)d_in[27];

    const int NI  = in_sizes[0] / DD;
    const int NN  = in_sizes[1] / DD;
    const int Eii = in_sizes[2] / 2;
    const int Ein = in_sizes[3] / 2;
    const int Eni = in_sizes[4] / 2;
    const int B   = out_size / (2 * DD);
    float* out = (float*)d_out;

    const int nbins_i = (NI + BINW - 1) / BINW;
    const int nbins_n = (NN + BINW - 1) / BINW;
    const int nbins_max = (nbins_i > nbins_n) ? nbins_i : nbins_n;
    const int nblk_ii = cdiv(Eii, SL);
    const int nblk_ni = cdiv(Eni, SL);
    const int nblk_in = cdiv(Ein, SL);
    int nblk_max = nblk_ii;
    if (nblk_ni > nblk_max) nblk_max = nblk_ni;
    if (nblk_in > nblk_max) nblk_max = nblk_in;

    float* ws = (float*)d_ws;
    float2* kv_i = (float2*)ws;  ws += 2L * NI;
    float*  q_i  = ws;           ws += NI;
    float2* kv_n = (float2*)ws;  ws += 2L * NN;
    float*  q_n  = ws;           ws += NN;
    float* sc_i = ws;   ws += NI;
    float* sc_n = ws;   ws += NN;
    float* ew_i = ws;   ws += NI;
    float* ew_n = ws;   ws += NN;
    // zero-init region (sg must be zeroed: accum merges with atomics)
    float* zro0 = ws;
    float2* sg_i = (float2*)ws;  ws += 2L * NI;
    float2* sg_n = (float2*)ws;  ws += 2L * NN;
    float* bsum_i = ws; ws += B;
    float* bsum_n = ws; ws += B;
    float* maxk_i = ws; ws += 1;
    float* maxk_n = ws; ws += 1;
    float* wsum_i = ws; ws += 1;
    float* wsum_n = ws; ws += 1;
    float* C_inst = ws; ws += 1;
    float* C_net  = ws; ws += 1;
    long n_zro = (long)(ws - zro0);
    // -inf region
    float* neg0 = ws;
    float* bmax_i = ws; ws += B;
    float* bmax_n = ws; ws += B;
    long n_neg = (long)(ws - neg0);
    // partition buffers (reused across the three edge types, processed sequentially)
    int* hist = (int*)ws;          ws += (long)nblk_max * 256;
    int* base = (int*)ws;          ws += (long)nblk_max * 256;
    int* cnt  = (int*)ws;          ws += 256;
    unsigned int* pay = (unsigned int*)ws;  ws += (long)nbins_max * CAP;

    dim3 blk(256);

    init_kernel<<<256, blk, 0, stream>>>(out, (long)out_size, zro0, n_zro, neg0, n_neg);
    wsum_kernel<<<2, blk, 0, stream>>>(w_i, w_n, wsum_i, wsum_n);

    kqv_kernel<<<2048, blk, 0, stream>>>(x_i, W_i, bW_i, kv_i, q_i, maxk_i, NI);
    kqv_kernel<<<2048, blk, 0, stream>>>(x_n, W_n, bW_n, kv_n, q_n, maxk_n, NN);

    prep_kernel<<<1, 64, 0, stream>>>(a_ii, p_ii, a_ni, p_ni, a_in, p_in,
                                      maxk_i, maxk_n, C_inst, C_net);

    // type ii -> sg_i
    hist_kernel<<<nblk_ii, blk, 0, stream>>>(e_ii + Eii, hist, Eii);
    scan_kernel<<<nbins_i, 64, 0, stream>>>(hist, base, cnt, nblk_ii);
    fill_kernel<<<nblk_ii, blk, 0, stream>>>(e_ii, e_ii + Eii, base, pay, Eii);
    accum_kernel<<<nbins_i * ASPLIT, blk, 0, stream>>>(pay, cnt, kv_i, q_i,
                                                       a_ii, p_ii, m_ii, C_inst, sg_i, NI);
    // type ni -> sg_i
    hist_kernel<<<nblk_ni, blk, 0, stream>>>(e_ni + Eni, hist, Eni);
    scan_kernel<<<nbins_i, 64, 0, stream>>>(hist, base, cnt, nblk_ni);
    fill_kernel<<<nblk_ni, blk, 0, stream>>>(e_ni, e_ni + Eni, base, pay, Eni);
    accum_kernel<<<nbins_i * ASPLIT, blk, 0, stream>>>(pay, cnt, kv_n, q_i,
                                                       a_ni, p_ni, m_ni, C_inst, sg_i, NI);
    // type in -> sg_n
    hist_kernel<<<nblk_in, blk, 0, stream>>>(e_in + Ein, hist, Ein);
    scan_kernel<<<nbins_n, 64, 0, stream>>>(hist, base, cnt, nblk_in);
    fill_kernel<<<nblk_in, blk, 0, stream>>>(e_in, e_in + Ein, base, pay, Ein);
    accum_kernel<<<nbins_n * ASPLIT, blk, 0, stream>>>(pay, cnt, kv_i, q_n,
                                                       a_in, p_in, m_in, C_net, sg_n, NN);

    score_bmax_kernel<<<cdiv(NI, 256), blk, 0, stream>>>(sg_i, outw_i, outb_i, wsum_i, b_i,
                                                         bat_i, sc_i, bmax_i, NI);
    score_bmax_kernel<<<cdiv(NN, 256), blk, 0, stream>>>(sg_n, outw_n, outb_n, wsum_n, b_n,
                                                         bat_n, sc_n, bmax_n, NN);
    bsum_kernel<<<cdiv(NI, 256), blk, 0, stream>>>(sc_i, bat_i, bmax_i, bsum_i, ew_i, NI);
    bsum_kernel<<<cdiv(NN, 256), blk, 0, stream>>>(sc_n, bat_n, bmax_n, bsum_n, ew_n, NN);

    pool_kernel<<<cdiv(cdiv(NI, NPW), 4), blk, 0, stream>>>(x_i, ew_i, bat_i, bsum_i, out, NI);
    pool_kernel<<<cdiv(cdiv(NN, NPW), 4), blk, 0, stream>>>(x_n, ew_n, bat_n, bsum_n, out + (long)B * DD, NN);
}

// Round 13
// 1203.295 us; speedup vs baseline: 1.5181x; 1.0321x over previous
//
#include <hip/hip_runtime.h>
#include <cmath>

#define DD 256
#define BINW 1024          // destinations per bin (fits LDS accumulators)
#define CAP 16384          // payload slots per bin (mean 15360, +8 sigma)
#define SL 4096            // edges per hist/fill block
#define NPW 32             // nodes per wave in pooling
#define ASPLIT 4           // blocks per bin in accum

static inline int cdiv(long a, long b) { return (int)((a + b - 1) / b); }

__device__ __forceinline__ void atomic_max_float(float* addr, float value) {
    if (value >= 0.0f) atomicMax((int*)addr, __float_as_int(value));
    else atomicMin((unsigned int*)addr, __float_as_uint(value));
}

// ---------------- init: zero out/sg/bsum/..., -inf bmax ----------------
__global__ void init_kernel(float* __restrict__ out, long nout,
                            float* __restrict__ zro, long nz,
                            float* __restrict__ neg, long nneg) {
    long i = (long)blockIdx.x * blockDim.x + threadIdx.x;
    long st = (long)gridDim.x * blockDim.x;
    for (long t = i; t < nout; t += st) out[t] = 0.0f;
    for (long t = i; t < nz; t += st) zro[t] = 0.0f;
    for (long t = i; t < nneg; t += st) neg[t] = -INFINITY;
}

// ---------------- wsum: sum of the (1,D) score weight rows ----------------
__global__ void wsum_kernel(const float* __restrict__ w0, const float* __restrict__ w1,
                            float* __restrict__ o0, float* __restrict__ o1) {
    __shared__ float sm[DD];
    const float* w = (blockIdx.x == 0) ? w0 : w1;
    sm[threadIdx.x] = w[threadIdx.x];
    __syncthreads();
    for (int s = DD / 2; s > 0; s >>= 1) {
        if (threadIdx.x < s) sm[threadIdx.x] += sm[threadIdx.x + s];
        __syncthreads();
    }
    if (threadIdx.x == 0) {
        if (blockIdx.x == 0) *o0 = sm[0]; else *o1 = sm[0];
    }
}

// ---------------- kqv: 16-lane-group reduction, 4 nodes/wave-iter ----------------
// Lane sub=lane&15 owns features d = i*64 + sub*4 + j (i=0..3, j=0..3): load i is a
// fully-coalesced 256B segment per 16-lane group. Reduction = 4 shfl stages (vs 6 at
// width 64), 3 shuffles/node instead of 18.
__global__ void kqv_kernel(const float* __restrict__ x, const float* __restrict__ W,
                           const float* __restrict__ bias,
                           float2* __restrict__ kv, float* __restrict__ q,
                           float* __restrict__ maxk, int N) {
    const int lane = threadIdx.x & 63;
    const int sub  = lane & 15;       // feature group within node
    const int nsub = lane >> 4;       // node index within wave quad (0..3)
    const int wib  = threadIdx.x >> 6;
    const int wpb  = blockDim.x >> 6;
    long wid = (long)blockIdx.x * wpb + wib;
    long nw  = (long)gridDim.x * wpb;
    float wk[16], wq[16], wv[16];
#pragma unroll
    for (int i = 0; i < 4; i++) {
#pragma unroll
        for (int j = 0; j < 4; j++) {
            int d = i * 64 + sub * 4 + j;
            wk[i * 4 + j] = W[d * 3 + 0];
            wq[i * 4 + j] = W[d * 3 + 1];
            wv[i * 4 + j] = W[d * 3 + 2];
        }
    }
    const float bk = bias[0], bq = bias[1], bv = bias[2];
    const float4* x4 = (const float4*)x;
    float amax = 0.0f;
    long nquad = ((long)N + 3) >> 2;
    for (long t = wid; t < nquad; t += nw) {
        long n = t * 4 + nsub;
        float pk = 0.0f, pq = 0.0f, pv = 0.0f;
        if (n < N) {
#pragma unroll
            for (int i = 0; i < 4; i++) {
                float4 xv = x4[n * 64 + i * 16 + sub];
                pk += xv.x * wk[i*4+0] + xv.y * wk[i*4+1] + xv.z * wk[i*4+2] + xv.w * wk[i*4+3];
                pq += xv.x * wq[i*4+0] + xv.y * wq[i*4+1] + xv.z * wq[i*4+2] + xv.w * wq[i*4+3];
                pv += xv.x * wv[i*4+0] + xv.y * wv[i*4+1] + xv.z * wv[i*4+2] + xv.w * wv[i*4+3];
            }
        }
#pragma unroll
        for (int mk = 1; mk < 16; mk <<= 1) {
            pk += __shfl_xor(pk, mk, 64);
            pq += __shfl_xor(pq, mk, 64);
            pv += __shfl_xor(pv, mk, 64);
        }
        if (sub == 0 && n < N) {
            float kk = pk + bk;
            amax = fmaxf(amax, fabsf(kk));
            kv[n] = make_float2(kk, pv + bv);
            q[n]  = pq + bq;
        }
    }
#pragma unroll
    for (int mk = 1; mk < 64; mk <<= 1) amax = fmaxf(amax, __shfl_xor(amax, mk, 64));
    if (lane == 0) atomic_max_float(maxk, amax);
}

// ---------------- prep: logit upper-bound coefficients ----------------
__global__ void prep_kernel(const float* a_ii, const float* p_ii,
                            const float* a_ni, const float* p_ni,
                            const float* a_in, const float* p_in,
                            const float* maxk_i, const float* maxk_n,
                            float* __restrict__ C_inst, float* __restrict__ C_net) {
    if (threadIdx.x == 0 && blockIdx.x == 0) {
        float ci = fmaxf(fabsf(a_ii[0] * p_ii[0]) * maxk_i[0],
                         fabsf(a_ni[0] * p_ni[0]) * maxk_n[0]);
        float cn = fabsf(a_in[0] * p_in[0]) * maxk_i[0];
        *C_inst = ci;
        *C_net  = cn;
    }
}

// ---------------- hist: per-block bin histogram (plain stores, no global atomics) ----------------
__global__ __launch_bounds__(256) void hist_kernel(const int* __restrict__ dst,
                                                   int* __restrict__ hist, int E) {
    __shared__ int h[256];
    const int tid = threadIdx.x;
    h[tid] = 0;
    __syncthreads();
    long e0 = (long)blockIdx.x * SL;
    long e1 = e0 + SL; if (e1 > E) e1 = E;
    for (long e = e0 + tid; e < e1; e += 256) {
        atomicAdd(&h[dst[e] >> 10], 1);
    }
    __syncthreads();
    hist[(long)blockIdx.x * 256 + tid] = h[tid];
}

// ---------------- scan: per-bin exclusive prefix over blocks -> per-block bases ----------------
__global__ void scan_kernel(const int* __restrict__ hist, int* __restrict__ base,
                            int* __restrict__ cnt, int nblk) {
    const int b = blockIdx.x;
    const int lane = threadIdx.x;
    int running = 0;
    for (int blk0 = 0; blk0 < nblk; blk0 += 64) {
        int blk = blk0 + lane;
        int v = (blk < nblk) ? hist[(long)blk * 256 + b] : 0;
        int x = v;
#pragma unroll
        for (int off = 1; off < 64; off <<= 1) {
            int y = __shfl_up(x, off, 64);
            if (lane >= off) x += y;
        }
        if (blk < nblk) base[(long)blk * 256 + b] = b * CAP + running + (x - v);
        running += __shfl(x, 63, 64);
    }
    if (lane == 0) cnt[b] = running;
}

// ---------------- fill: scatter packed (src<<10 | dst&1023) at precomputed bases ----------------
__global__ __launch_bounds__(256) void fill_kernel(
    const int* __restrict__ src, const int* __restrict__ dst,
    const int* __restrict__ base_g, unsigned int* __restrict__ pay, int E) {
    __shared__ int bl[256];
    __shared__ int off[256];
    const int tid = threadIdx.x;
    bl[tid] = base_g[(long)blockIdx.x * 256 + tid];
    off[tid] = 0;
    __syncthreads();
    long e0 = (long)blockIdx.x * SL;
    long e1 = e0 + SL; if (e1 > E) e1 = E;
    for (long e = e0 + tid; e < e1; e += 256) {
        int d = dst[e], s = src[e];
        int b = d >> 10;
        int o = atomicAdd(&off[b], 1);
        long slot = (long)bl[b] + o;
        if (slot < (long)(b + 1) * CAP) {
            pay[slot] = ((unsigned int)s << 10) | (unsigned int)(d & (BINW - 1));
        }
    }
}

// ---------------- accum: per-bin-stripe LDS accumulation, atomic merge into sg ----------------
__global__ __launch_bounds__(256) void accum_kernel(
    const unsigned int* __restrict__ pay, const int* __restrict__ cnt,
    const float2* __restrict__ kv, const float* __restrict__ q,
    const float* __restrict__ a_p, const float* __restrict__ p_p,
    const float* __restrict__ msc_p, const float* __restrict__ C_p,
    float2* __restrict__ sg, int N) {
    __shared__ float accS[BINW];
    __shared__ float accG[BINW];
    __shared__ float2 qm[BINW];
    const int tid = threadIdx.x;
    const int b  = blockIdx.x >> 2;      // ASPLIT = 4
    const int sp = blockIdx.x & 3;
    const float C = C_p[0];
    const float coef = a_p[0] * p_p[0];
    const float msc  = msc_p[0];
    for (int i = tid; i < BINW; i += 256) {
        accS[i] = 0.0f; accG[i] = 0.0f;
        int d = b * BINW + i;
        float qd = (d < N) ? q[d] : 0.0f;
        qm[i] = make_float2(qd, fabsf(qd) * C);
    }
    __syncthreads();
    long s0 = (long)b * CAP;
    long c = cnt[b];
    if (c > CAP) c = CAP;
    long chunk = (c + ASPLIT - 1) / ASPLIT;
    long a0 = s0 + (long)sp * chunk;
    long a1 = a0 + chunk;
    long send = s0 + c;
    if (a1 > send) a1 = send;
    for (long e = a0 + tid; e < a1; e += 256) {
        unsigned int pk = pay[e];
        int s  = (int)(pk >> 10);
        int di = (int)(pk & (BINW - 1));
        float2 kvv = kv[s];
        float2 qv = qm[di];
        float ex = __expf(qv.x * (kvv.x * coef) - qv.y);
        atomicAdd(&accS[di], ex);
        atomicAdd(&accG[di], ex * (kvv.y * msc));
    }
    __syncthreads();
    float* sgf = (float*)sg;
    for (int i = tid; i < BINW; i += 256) {
        int d = b * BINW + i;
        if (d < N) {
            float s = accS[i];
            if (s != 0.0f) {
                unsafeAtomicAdd(&sgf[2L * d],     s);
                unsafeAtomicAdd(&sgf[2L * d + 1], accG[i]);
            }
        }
    }
}

// ---------------- fused node epilogue + batch segment max ----------------
__global__ void score_bmax_kernel(const float2* __restrict__ sg,
                                  const float* __restrict__ outw_p, const float* __restrict__ outb_p,
                                  const float* __restrict__ wsum_p, const float* __restrict__ bsc_p,
                                  const int* __restrict__ batch,
                                  float* __restrict__ score, float* __restrict__ bmax, int N) {
    const float ow = outw_p[0], ob = outb_p[0];
    const float wsum = wsum_p[0], badd = bsc_p[0] * (float)DD;
    const int lane = threadIdx.x & 63;
    long st = (long)gridDim.x * blockDim.x;
    for (long base = (long)blockIdx.x * blockDim.x; base < N; base += st) {
        long n = base + threadIdx.x;
        bool act = (n < N);
        int b = act ? batch[n] : -1;
        float v = -INFINITY;
        if (act) {
            float2 t = sg[n];
            float a  = t.y / (t.x + 1e-30f);
            float at = 0.5f * a * (1.0f + erff(a * 0.7071067811865475f));
            v = (at * ow + ob) * wsum + badd;
            score[n] = v;
        }
        int b0 = __shfl(b, 0, 64);
        if (__all(b == b0)) {
#pragma unroll
            for (int mk = 1; mk < 64; mk <<= 1) v = fmaxf(v, __shfl_xor(v, mk, 64));
            if (lane == 0 && b0 >= 0) atomic_max_float(&bmax[b0], v);
        } else if (act) {
            atomic_max_float(&bmax[b], v);
        }
    }
}

// ---------------- batch segment exp-sum; stores per-node e ----------------
__global__ void bsum_kernel(const float* __restrict__ score, const int* __restrict__ batch,
                            const float* __restrict__ bmax,
                            float* __restrict__ bsum, float* __restrict__ ew, int N) {
    const int lane = threadIdx.x & 63;
    long st = (long)gridDim.x * blockDim.x;
    for (long base = (long)blockIdx.x * blockDim.x; base < N; base += st) {
        long n = base + threadIdx.x;
        bool act = (n < N);
        int b = act ? batch[n] : -1;
        float ex = 0.0f;
        if (act) {
            ex = __expf(score[n] - bmax[b]);
            ew[n] = ex;
        }
        int b0 = __shfl(b, 0, 64);
        if (__all(b == b0)) {
#pragma unroll
            for (int mk = 1; mk < 64; mk <<= 1) ex += __shfl_xor(ex, mk, 64);
            if (lane == 0 && b0 >= 0) unsafeAtomicAdd(&bsum[b0], ex);
        } else if (act) {
            unsafeAtomicAdd(&bsum[b], ex);
        }
    }
}

// ---------------- pooling: wave per NPW-node run, flush at batch boundaries ----------------
__global__ void pool_kernel(const float* __restrict__ x, const float* __restrict__ ew,
                            const int* __restrict__ batch, const float* __restrict__ bsum,
                            float* __restrict__ out, int N) {
    const int lane = threadIdx.x & 63;
    const int wib  = threadIdx.x >> 6;
    const int wpb  = blockDim.x >> 6;
    long w = (long)blockIdx.x * wpb + wib;
    long n0 = w * NPW;
    if (n0 >= N) return;
    long n1 = n0 + NPW; if (n1 > N) n1 = N;
    const float4* x4 = (const float4*)x;
    float4 acc = make_float4(0.f, 0.f, 0.f, 0.f);
    int pb = batch[n0];
    for (long n = n0; n < n1; ++n) {
        int b = batch[n];
        if (b != pb) {
            float* p = out + (long)pb * DD + lane * 4;
            unsafeAtomicAdd(p + 0, acc.x);
            unsafeAtomicAdd(p + 1, acc.y);
            unsafeAtomicAdd(p + 2, acc.z);
            unsafeAtomicAdd(p + 3, acc.w);
            acc = make_float4(0.f, 0.f, 0.f, 0.f);
            pb = b;
        }
        float wt = ew[n] / (bsum[b] + 1e-16f);
        float4 xv = x4[n * 64 + lane];
        acc.x += wt * xv.x;
        acc.y += wt * xv.y;
        acc.z += wt * xv.z;
        acc.w += wt * xv.w;
    }
    float* p = out + (long)pb * DD + lane * 4;
    unsafeAtomicAdd(p + 0, acc.x);
    unsafeAtomicAdd(p + 1, acc.y);
    unsafeAtomicAdd(p + 2, acc.z);
    unsafeAtomicAdd(p + 3, acc.w);
}

extern "C" void kernel_launch(void* const* d_in, const int* in_sizes, int n_in,
                              void* d_out, int out_size, void* d_ws, size_t ws_size,
                              hipStream_t stream) {
    const float* x_i    = (const float*)d_in[0];
    const float* x_n    = (const float*)d_in[1];
    const int*   e_ii   = (const int*)d_in[2];
    const int*   e_in   = (const int*)d_in[3];
    const int*   e_ni   = (const int*)d_in[4];
    const int*   bat_i  = (const int*)d_in[5];
    const int*   bat_n  = (const int*)d_in[6];
    const float* W_i    = (const float*)d_in[7];
    const float* bW_i   = (const float*)d_in[8];
    const float* W_n    = (const float*)d_in[9];
    const float* bW_n   = (const float*)d_in[10];
    const float* a_ii   = (const float*)d_in[11];
    const float* m_ii   = (const float*)d_in[12];
    const float* p_ii   = (const float*)d_in[13];
    const float* a_in   = (const float*)d_in[14];
    const float* m_in   = (const float*)d_in[15];
    const float* p_in   = (const float*)d_in[16];
    const float* a_ni   = (const float*)d_in[17];
    const float* m_ni   = (const float*)d_in[18];
    const float* p_ni   = (const float*)d_in[19];
    const float* outw_i = (const float*)d_in[20];
    const float* outb_i = (const float*)d_in[21];
    const float* outw_n = (const float*)d_in[22];
    const float* outb_n = (const float*)d_in[23];
    const float* w_i    = (const float*)d_in[24];
    const float* b_i    = (const float*)d_in[25];
    const float* w_n    = (const float*)d_in[26];
    const float* b_n    = (const float*)d_in[27];

    const int NI  = in_sizes[0] / DD;
    const int NN  = in_sizes[1] / DD;
    const int Eii = in_sizes[2] / 2;
    const int Ein = in_sizes[3] / 2;
    const int Eni = in_sizes[4] / 2;
    const int B   = out_size / (2 * DD);
    float* out = (float*)d_out;

    const int nbins_i = (NI + BINW - 1) / BINW;
    const int nbins_n = (NN + BINW - 1) / BINW;
    const int nbins_max = (nbins_i > nbins_n) ? nbins_i : nbins_n;
    const int nblk_ii = cdiv(Eii, SL);
    const int nblk_ni = cdiv(Eni, SL);
    const int nblk_in = cdiv(Ein, SL);
    int nblk_max = nblk_ii;
    if (nblk_ni > nblk_max) nblk_max = nblk_ni;
    if (nblk_in > nblk_max) nblk_max = nblk_in;

    float* ws = (float*)d_ws;
    float2* kv_i = (float2*)ws;  ws += 2L * NI;
    float*  q_i  = ws;           ws += NI;
    float2* kv_n = (float2*)ws;  ws += 2L * NN;
    float*  q_n  = ws;           ws += NN;
    float* sc_i = ws;   ws += NI;
    float* sc_n = ws;   ws += NN;
    float* ew_i = ws;   ws += NI;
    float* ew_n = ws;   ws += NN;
    // zero-init region (sg must be zeroed: accum merges with atomics)
    float* zro0 = ws;
    float2* sg_i = (float2*)ws;  ws += 2L * NI;
    float2* sg_n = (float2*)ws;  ws += 2L * NN;
    float* bsum_i = ws; ws += B;
    float* bsum_n = ws; ws += B;
    float* maxk_i = ws; ws += 1;
    float* maxk_n = ws; ws += 1;
    float* wsum_i = ws; ws += 1;
    float* wsum_n = ws; ws += 1;
    float* C_inst = ws; ws += 1;
    float* C_net  = ws; ws += 1;
    long n_zro = (long)(ws - zro0);
    // -inf region
    float* neg0 = ws;
    float* bmax_i = ws; ws += B;
    float* bmax_n = ws; ws += B;
    long n_neg = (long)(ws - neg0);
    // partition buffers (reused across the three edge types, processed sequentially)
    int* hist = (int*)ws;          ws += (long)nblk_max * 256;
    int* base = (int*)ws;          ws += (long)nblk_max * 256;
    int* cnt  = (int*)ws;          ws += 256;
    unsigned int* pay = (unsigned int*)ws;  ws += (long)nbins_max * CAP;

    dim3 blk(256);

    init_kernel<<<256, blk, 0, stream>>>(out, (long)out_size, zro0, n_zro, neg0, n_neg);
    wsum_kernel<<<2, blk, 0, stream>>>(w_i, w_n, wsum_i, wsum_n);

    kqv_kernel<<<2048, blk, 0, stream>>>(x_i, W_i, bW_i, kv_i, q_i, maxk_i, NI);
    kqv_kernel<<<2048, blk, 0, stream>>>(x_n, W_n, bW_n, kv_n, q_n, maxk_n, NN);

    prep_kernel<<<1, 64, 0, stream>>>(a_ii, p_ii, a_ni, p_ni, a_in, p_in,
                                      maxk_i, maxk_n, C_inst, C_net);

    // type ii -> sg_i
    hist_kernel<<<nblk_ii, blk, 0, stream>>>(e_ii + Eii, hist, Eii);
    scan_kernel<<<nbins_i, 64, 0, stream>>>(hist, base, cnt, nblk_ii);
    fill_kernel<<<nblk_ii, blk, 0, stream>>>(e_ii, e_ii + Eii, base, pay, Eii);
    accum_kernel<<<nbins_i * ASPLIT, blk, 0, stream>>>(pay, cnt, kv_i, q_i,
                                                       a_ii, p_ii, m_ii, C_inst, sg_i, NI);
    // type ni -> sg_i
    hist_kernel<<<nblk_ni, blk, 0, stream>>>(e_ni + Eni, hist, Eni);
    scan_kernel<<<nbins_i, 64, 0, stream>>>(hist, base, cnt, nblk_ni);
    fill_kernel<<<nblk_ni, blk, 0, stream>>>(e_ni, e_ni + Eni, base, pay, Eni);
    accum_kernel<<<nbins_i * ASPLIT, blk, 0, stream>>>(pay, cnt, kv_n, q_i,
                                                       a_ni, p_ni, m_ni, C_inst, sg_i, NI);
    // type in -> sg_n
    hist_kernel<<<nblk_in, blk, 0, stream>>>(e_in + Ein, hist, Ein);
    scan_kernel<<<nbins_n, 64, 0, stream>>>(hist, base, cnt, nblk_in);
    fill_kernel<<<nblk_in, blk, 0, stream>>>(e_in, e_in + Ein, base, pay, Ein);
    accum_kernel<<<nbins_n * ASPLIT, blk, 0, stream>>>(pay, cnt, kv_i, q_n,
                                                       a_in, p_in, m_in, C_net, sg_n, NN);

    score_bmax_kernel<<<cdiv(NI, 256), blk, 0, stream>>>(sg_i, outw_i, outb_i, wsum_i, b_i,
                                                         bat_i, sc_i, bmax_i, NI);
    score_bmax_kernel<<<cdiv(NN, 256), blk, 0, stream>>>(sg_n, outw_n, outb_n, wsum_n, b_n,
                                                         bat_n, sc_n, bmax_n, NN);
    bsum_kernel<<<cdiv(NI, 256), blk, 0, stream>>>(sc_i, bat_i, bmax_i, bsum_i, ew_i, NI);
    bsum_kernel<<<cdiv(NN, 256), blk, 0, stream>>>(sc_n, bat_n, bmax_n, bsum_n, ew_n, NN);

    pool_kernel<<<cdiv(cdiv(NI, NPW), 4), blk, 0, stream>>>(x_i, ew_i, bat_i, bsum_i, out, NI);
    pool_kernel<<<cdiv(cdiv(NN, NPW), 4), blk, 0, stream>>>(x_n, ew_n, bat_n, bsum_n, out + (long)B * DD, NN);
}